// Round 5
// baseline (448.414 us; speedup 1.0000x reference)
//
#include <hip/hip_runtime.h>

#define Bn 512
#define Ln 2048
#define Kn 19
#define NEGV (-1000.0f)
#define START_IDn 17
#define PAD_IDn 18
#define SEG 64               // checkpoint segment (steps)
#define PBYTES 79691776u     // 512*2048*19*4

// ---------------------------------------------------------------------------
// R10: R9's producer-consumer fusion, with rec engines evicted from the LDS
// pipe. R9 post-mortem: rec's ~7 DS ops/step queued fwd's latency-critical
// ds_write->5x ds_read chain (+84cy/step, fwd 238->310us). Now each rec
// engine is a FULL wave (waves 1-4; (half, seg-parity) each) that gathers dp
// via 19 v_readlane from lanes 0..18 — hazard nops burn only the rec wave's
// own issue slots (its SIMD is otherwise idle), and rec DS traffic drops to
// ~1 byte-write/step + sparse flag polls. fwd (wave 0) is the R5-exact core
// (proven 238us) at setprio(1). Checkpoint/flag protocol unchanged from R9
// (proven correct). Same adds + same max-tree order => bit-identical cand/
// best => identical first-index argmax. crf_bwd unchanged.
// ---------------------------------------------------------------------------

// fwd per-step core (R5-exact): cand[p] = dp[p] + Trow[p] from LDS round-trip.
#define DP_CORE(BASE)                                                          \
    float4 q0 = *(const float4*)((BASE) + 0);                                  \
    float4 q1 = *(const float4*)((BASE) + 4);                                  \
    float4 q2 = *(const float4*)((BASE) + 8);                                  \
    float4 q3 = *(const float4*)((BASE) + 12);                                 \
    float4 q4 = *(const float4*)((BASE) + 16); /* .w junk, unused */           \
    float cand[Kn];                                                            \
    cand[0]  = q0.x + Trow[0];  cand[1]  = q0.y + Trow[1];                     \
    cand[2]  = q0.z + Trow[2];  cand[3]  = q0.w + Trow[3];                     \
    cand[4]  = q1.x + Trow[4];  cand[5]  = q1.y + Trow[5];                     \
    cand[6]  = q1.z + Trow[6];  cand[7]  = q1.w + Trow[7];                     \
    cand[8]  = q2.x + Trow[8];  cand[9]  = q2.y + Trow[9];                     \
    cand[10] = q2.z + Trow[10]; cand[11] = q2.w + Trow[11];                    \
    cand[12] = q3.x + Trow[12]; cand[13] = q3.y + Trow[13];                    \
    cand[14] = q3.z + Trow[14]; cand[15] = q3.w + Trow[15];                    \
    cand[16] = q4.x + Trow[16]; cand[17] = q4.y + Trow[17];                    \
    cand[18] = q4.z + Trow[18];                                                \
    MAXTREE()

// shared exact max tree (identical op order in fwd and rec => bit-exact)
#define MAXTREE()                                                              \
    float m0 = fmaxf(fmaxf(cand[0],  cand[1]),  cand[2]);                      \
    float m1 = fmaxf(fmaxf(cand[3],  cand[4]),  cand[5]);                      \
    float m2 = fmaxf(fmaxf(cand[6],  cand[7]),  cand[8]);                      \
    float m3 = fmaxf(fmaxf(cand[9],  cand[10]), cand[11]);                     \
    float m4 = fmaxf(fmaxf(cand[12], cand[13]), cand[14]);                     \
    float m5 = fmaxf(fmaxf(cand[15], cand[16]), cand[17]);                     \
    float n0 = fmaxf(fmaxf(m0, m1), m2);                                       \
    float n1 = fmaxf(fmaxf(m3, m4), cand[18]);                                 \
    float best = fmaxf(fmaxf(n0, n1), m5);

// rec per-step core: dp gathered by wave-wide readlane (dp[p] lives in lane p).
// Same float adds and same tree => bit-identical to DP_CORE's results.
#define RL(p) (__uint_as_float((unsigned)__builtin_amdgcn_readlane(            \
                   (int)__float_as_uint(mydp), (p))) + Trow[p])
#define REC_CORE()                                                             \
    float cand[Kn];                                                            \
    cand[0]  = RL(0);  cand[1]  = RL(1);  cand[2]  = RL(2);                    \
    cand[3]  = RL(3);  cand[4]  = RL(4);  cand[5]  = RL(5);                    \
    cand[6]  = RL(6);  cand[7]  = RL(7);  cand[8]  = RL(8);                    \
    cand[9]  = RL(9);  cand[10] = RL(10); cand[11] = RL(11);                   \
    cand[12] = RL(12); cand[13] = RL(13); cand[14] = RL(14);                   \
    cand[15] = RL(15); cand[16] = RL(16); cand[17] = RL(17);                   \
    cand[18] = RL(18);                                                         \
    MAXTREE()

// ---------------------------------------------------------------------------
__global__ __launch_bounds__(320, 1) void crf_fused(
    const float* __restrict__ P, const float* __restrict__ T,
    const int* __restrict__ mask, float* __restrict__ dpfin,
    int* __restrict__ lens, unsigned char* __restrict__ choice)
{
    const int tid = threadIdx.x;
    const int w = tid >> 6;              // wave 0 = fwd; waves 1-4 = rec engines

    // --- shared state -------------------------------------------------------
    __shared__ float dp[2][32];                    // fwd DP round-trip
    __shared__ float ebuf[2][2][1280];             // fwd emission staging
    __shared__ float ckbuf[2][32][20];             // checkpoints [half][seg][tag]
    __shared__ int   s_len2[2];
    __shared__ int   seg_done[2];                  // #checkpoints published/half
    __shared__ __align__(16) unsigned char rcbuf[4][1280];  // rec bp staging

    if (tid < 2) *(volatile int*)&seg_done[tid] = 0;
    __syncthreads();                               // all 5 waves, once

    if (w == 0) {
        // ===================== FWD wave (R5-identical core) =================
        __builtin_amdgcn_s_setprio(1);             // protect the serial chain
        const int lane = tid;
        const int half = lane >> 5;
        const int c = lane & 31;
        const int b = blockIdx.x * 2 + half;
        const int cc = (c < Kn) ? c : (Kn - 1);

        float Trow[Kn];
#pragma unroll
        for (int p = 0; p < Kn; ++p) Trow[p] = T[cc * Kn + p];

        // length = popcount of contiguous-prefix mask row
        const int* mrow = mask + (size_t)b * Ln;
        int sum = 0;
#pragma unroll
        for (int j = 0; j < Ln / 128; ++j) {
            int4 v = *(const int4*)(mrow + j * 128 + c * 4);
            sum += v.x + v.y + v.z + v.w;
        }
#pragma unroll
        for (int k = 1; k < 32; k <<= 1) sum += __shfl_xor(sum, k, 64);
        const int len = sum;
        if (c == 0) { lens[b] = len; s_len2[half] = len; }
        const int lenO = __shfl_xor(len, 32, 64);
        int maxlen = len > lenO ? len : lenO;
        int lmin = len < lenO ? len : lenO;
        lmin = __builtin_amdgcn_readfirstlane(lmin);
        int mlen = (maxlen + (SEG - 1)) & ~(SEG - 1);
        mlen = __builtin_amdgcn_readfirstlane(mlen);

        float mydp = (c == START_IDn) ? 0.0f : NEGV;
        dp[half][c] = mydp;

        const unsigned bbyte = (unsigned)b * (Ln * Kn * 4u);
        const unsigned limit = PBYTES - 16;
        const char* Pc = (const char*)P;
        float4 r[10];

#define STAGE_LOAD(ci)                                                         \
    { unsigned base_ = bbyte + (unsigned)(ci) * 4864u + ((unsigned)c << 4);    \
      _Pragma("unroll")                                                        \
      for (int i_ = 0; i_ < 10; ++i_) {                                        \
          unsigned o_ = base_ + (unsigned)i_ * 512u;                           \
          if (o_ > limit) o_ = limit;                                          \
          r[i_] = *(const float4*)(Pc + o_);                                   \
      } }
#define STAGE_WRITE(nb)                                                        \
    { float* d_ = &ebuf[nb][half][(unsigned)c << 2];                           \
      _Pragma("unroll")                                                        \
      for (int i_ = 0; i_ < 10; ++i_) *(float4*)(d_ + i_ * 128) = r[i_]; }

        int buf = 0;
        STAGE_LOAD(0);
        STAGE_WRITE(0);

        for (int t0 = 0; t0 < mlen; t0 += SEG) {
            // publish checkpoint (LDS), then release flag; DS pipe in-order
            if (c < Kn) ckbuf[half][t0 >> 6][c] = mydp;
            __threadfence_block();
            __asm__ __volatile__("" ::: "memory");
            if (c == 0) *(volatile int*)&seg_done[half] = (t0 >> 6) + 1;

            STAGE_LOAD((t0 >> 6) + 1);   // prefetch next segment's emissions
            const float* ebl = &ebuf[buf][half][0];

            if (t0 + SEG <= lmin) {
                for (int tt = 0; tt < SEG; tt += 8) {
#pragma unroll
                    for (int u = 0; u < 8; ++u) {
                        const float e = ebl[(tt + u) * Kn + cc];
                        const float* base_ = &dp[half][0];
                        DP_CORE(base_)
                        mydp = best + e;
                        dp[half][c] = mydp;
                    }
                }
            } else {
                for (int tt = 0; tt < SEG; tt += 8) {
#pragma unroll
                    for (int u = 0; u < 8; ++u) {
                        const int t = t0 + tt + u;
                        const float e = ebl[(tt + u) * Kn + cc];
                        const float* base_ = &dp[half][0];
                        DP_CORE(base_)
                        float nd = best + e;
                        mydp = (t < len) ? nd : mydp;
                        dp[half][c] = mydp;
                    }
                }
            }
            STAGE_WRITE(buf ^ 1);
            buf ^= 1;
        }
        if (c < Kn) dpfin[b * Kn + c] = mydp;
        // release any engine waiting on segments beyond mlen
        __threadfence_block();
        if (c == 0) *(volatile int*)&seg_done[half] = 32;
#undef STAGE_LOAD
#undef STAGE_WRITE
    } else {
        // ============ REC engines: 1 wave each, readlane dp gather ==========
        const int e = w - 1;                  // 0..3
        const int h = e & 1;                  // which half/batch
        const int par = e >> 1;               // segment parity
        const int lane = tid & 63;
        const int cc = (lane < Kn) ? lane : (Kn - 1);
        const int b = blockIdx.x * 2 + h;

        float Trow[Kn];
#pragma unroll
        for (int p = 0; p < Kn; ++p) Trow[p] = T[cc * Kn + p];

        const float* pbase = P + (size_t)b * Ln * Kn;
        volatile int* vf = &seg_done[h];

        while (*vf < 1) __builtin_amdgcn_s_sleep(8);
        __asm__ __volatile__("" ::: "memory");
        const int len = s_len2[h];            // published before flag 1

        for (int s = par; s * SEG < len; s += 2) {
            while (*vf < s + 1) __builtin_amdgcn_s_sleep(8);
            __asm__ __volatile__("" ::: "memory");

            const int t0 = s * SEG;
            float mydp = (lane < Kn) ? ckbuf[h][s][lane] : NEGV;
            const float* prow = pbase + (size_t)t0 * Kn;

            // rolling emission prefetch (depth 8)
            float eb[8];
#pragma unroll
            for (int u = 0; u < 8; ++u) eb[u] = prow[u * Kn + cc];

            for (int tt = 0; tt < SEG; tt += 8) {
#pragma unroll
                for (int u = 0; u < 8; ++u) {
                    const int t = t0 + tt + u;
                    REC_CORE()
                    float nd = best + eb[u];
                    mydp = (t < len) ? nd : mydp;

                    // first-index argmax (jnp.argmax tie-break), exact equality
                    int arg = Kn - 1;
#pragma unroll
                    for (int p = Kn - 2; p >= 0; --p)
                        arg = (cand[p] == best) ? p : arg;
                    if (lane < Kn)
                        rcbuf[e][(tt + u) * Kn + lane] = (unsigned char)arg;

                    // prefetch emission for local step tt+u+8 (clamped)
                    int tn = tt + u + 8;
                    int tloc = (t0 + tn < Ln) ? tn : (Ln - 1 - t0);
                    eb[u] = prow[tloc * Kn + cc];
                }
            }
            // bulk flush this segment's backpointers (steps >= len unread)
            {
                const int4* s4 = (const int4*)&rcbuf[e][0];
                int4* d4 = (int4*)(choice + (size_t)b * Ln * Kn + (size_t)t0 * Kn);
                for (int i = lane; i < (SEG * Kn) / 16; i += 64) d4[i] = s4[i];
            }
        }
    }
}

// ---------------------------------------------------------------------------
// Backtrace: unchanged (exact integer function-composition scan).
// ---------------------------------------------------------------------------
__global__ __launch_bounds__(384, 1) void crf_bwd(
    const float* __restrict__ T, const unsigned char* __restrict__ choice,
    const float* __restrict__ dpfin, const int* __restrict__ lens,
    int* __restrict__ out)
{
    __shared__ unsigned char comp[Ln * Kn];   // 38912 B
    __shared__ int vchain[17];
    __shared__ int s_last, s_len;

    const int b = blockIdx.x;
    const int tid = threadIdx.x;

    {
        const int4* src = (const int4*)(choice + (size_t)b * Ln * Kn);
        int4* dst = (int4*)comp;
        for (int i = tid; i < (Ln * Kn) / 16; i += 384) dst[i] = src[i];
    }
    if (tid == 0) {
        s_len = lens[b];
        float bestv = dpfin[b * Kn + 0] + T[PAD_IDn * Kn + 0];
        int bl = 0;
        for (int ci = 1; ci < Kn; ++ci) {
            float v = dpfin[b * Kn + ci] + T[PAD_IDn * Kn + ci];
            if (v > bestv) { bestv = v; bl = ci; }
        }
        s_last = bl;
    }
    __syncthreads();
    const int len = s_len;

    // Phase 1: suffix-compose within each 128-step chunk, in place.
    {
        const int wv = tid >> 6;
        const int lane = tid & 63;
        const int ch = wv * 3 + lane / Kn;
        const int c = lane % Kn;
        if (lane < 3 * Kn && ch < 16) {
            int cur = c;
            const int tb = ch * 128 + 127;
            for (int i = 0; i < 128; ++i) {
                const int t = tb - i;
                int nv = comp[t * Kn + cur];   // cur <= 18 always: in-bounds
                cur = (t < len) ? nv : cur;
                comp[t * Kn + c] = cur;
            }
        }
    }
    __syncthreads();

    // Phase 2: chunk-boundary chain
    if (tid == 0) {
        int v = s_last;
        vchain[16] = v;
        for (int ch = 15; ch >= 0; --ch) {
            v = comp[ch * 128 * Kn + v];
            vchain[ch] = v;
        }
    }
    __syncthreads();

    // Phase 3: emit path
    const int last = s_last;
    int* orow = out + (size_t)b * Ln;
    for (int t = tid; t < Ln; t += 384) {
        int val;
        if (t >= len) {
            val = -1;
        } else if (t == Ln - 1) {
            val = last;
        } else {
            const int tp = t + 1;
            const int vc = vchain[(tp >> 7) + 1];
            val = comp[tp * Kn + vc];
        }
        orow[t] = val;
    }
}

// ---------------------------------------------------------------------------
extern "C" void kernel_launch(void* const* d_in, const int* in_sizes, int n_in,
                              void* d_out, int out_size, void* d_ws, size_t ws_size,
                              hipStream_t stream)
{
    const float* P    = (const float*)d_in[0];
    const float* T    = (const float*)d_in[1];
    const int*   mask = (const int*)d_in[2];
    int* out = (int*)d_out;

    // workspace layout — same proven footprint; dpck not needed
    const size_t choice_bytes = (size_t)Bn * Ln * Kn;            // 19,922,944
    unsigned char* choice = (unsigned char*)d_ws;
    float* dpfin = (float*)((char*)d_ws + choice_bytes);         // 38,912 B
    int* lens = (int*)((char*)d_ws + choice_bytes + (size_t)Bn * Kn * 4);

    crf_fused<<<Bn / 2, 320, 0, stream>>>(P, T, mask, dpfin, lens, choice);
    crf_bwd<<<Bn, 384, 0, stream>>>(T, choice, dpfin, lens, out);
}